// Round 6
// baseline (226.017 us; speedup 1.0000x reference)
//
#include <hip/hip_runtime.h>

#define BS   256
#define RR   4
#define WW   128
#define NN   2048
#define HH   256
#define NT   1024
#define NWAVE (NT / 64)      // 16
#define RPW  (WW / NWAVE)    // 8 rows per wave in pass 2

typedef float nfloat4 __attribute__((ext_vector_type(4)));

__device__ __forceinline__ float wave_sum(float v) {
#pragma unroll
  for (int m = 32; m >= 1; m >>= 1) v += __shfl_xor(v, m, 64);
  return v;
}
__device__ __forceinline__ float wave_max(float v) {
#pragma unroll
  for (int m = 32; m >= 1; m >>= 1) v = fmaxf(v, __shfl_xor(v, m, 64));
  return v;
}
__device__ __forceinline__ float block_sum(float v, float* s_red) {
  const int tid = threadIdx.x;
  v = wave_sum(v);
  __syncthreads();
  if ((tid & 63) == 0) s_red[tid >> 6] = v;
  __syncthreads();
  float s = s_red[0];
#pragma unroll
  for (int i = 1; i < NWAVE; ++i) s += s_red[i];
  return s;
}
__device__ __forceinline__ float block_max(float v, float* s_red) {
  const int tid = threadIdx.x;
  v = wave_max(v);
  __syncthreads();
  if ((tid & 63) == 0) s_red[tid >> 6] = v;
  __syncthreads();
  float s = s_red[0];
#pragma unroll
  for (int i = 1; i < NWAVE; ++i) s = fmaxf(s, s_red[i]);
  return s;
}
__device__ __forceinline__ void block_max4(float v[RR], float* s_red4) {
  const int tid = threadIdx.x, lane = tid & 63, wid = tid >> 6;
#pragma unroll
  for (int m = 32; m >= 1; m >>= 1) {
#pragma unroll
    for (int r = 0; r < RR; ++r) v[r] = fmaxf(v[r], __shfl_xor(v[r], m, 64));
  }
  __syncthreads();
  if (lane == 0) {
#pragma unroll
    for (int r = 0; r < RR; ++r) s_red4[wid * RR + r] = v[r];
  }
  __syncthreads();
#pragma unroll
  for (int r = 0; r < RR; ++r) {
    float s = s_red4[r];
#pragma unroll
    for (int i = 1; i < NWAVE; ++i) s = fmaxf(s, s_red4[i * RR + r]);
    v[r] = s;
  }
}
__device__ __forceinline__ void block_sum4(float v[RR], float* s_red4) {
  const int tid = threadIdx.x, lane = tid & 63, wid = tid >> 6;
#pragma unroll
  for (int m = 32; m >= 1; m >>= 1) {
#pragma unroll
    for (int r = 0; r < RR; ++r) v[r] += __shfl_xor(v[r], m, 64);
  }
  __syncthreads();
  if (lane == 0) {
#pragma unroll
    for (int r = 0; r < RR; ++r) s_red4[wid * RR + r] = v[r];
  }
  __syncthreads();
#pragma unroll
  for (int r = 0; r < RR; ++r) {
    float s = s_red4[r];
#pragma unroll
    for (int i = 1; i < NWAVE; ++i) s += s_red4[i * RR + r];
    v[r] = s;
  }
}
__device__ __forceinline__ float gumbelf(float u) {
  return -logf(-logf(u + 1e-10f) + 1e-10f);
}

// One block per batch (grid 256 = 1/CU), 1024 threads (16 waves/CU).
// Phase A: stats over M (thread owns 2 columns, float2).
// Phase B: write softmax + analytic read softmax (no memory pass).
// Phase C: apply (wave owns 8 rows): mem_new write + m_erased + m_read.
__global__ __launch_bounds__(NT, 4) void explicit_mem_fused(
    const float* __restrict__ k_r, const float* __restrict__ m_t,
    const float* __restrict__ hx, const float* __restrict__ memory,
    const float* __restrict__ usage, const float* __restrict__ read_weights,
    const float* __restrict__ Wg, const float* __restrict__ bg,
    const float* __restrict__ noise_write, const float* __restrict__ noise_read,
    float* __restrict__ m_read, float* __restrict__ mem_new,
    float* __restrict__ usage_new, float* __restrict__ read_wt_out,
    float* __restrict__ m_erased)
{
  __shared__ float s_wm[WW];          // 0.5 KB tanh(m_t)
  __shared__ float s_rk[RR * WW];     // 2 KB   tanh(read keys)
  __shared__ float s_wt[NN];          // 8 KB   write weights
  __shared__ float s_rwt[RR][NN];     // 32 KB  read weights
  __shared__ float s_red[NWAVE * RR]; // reduction scratch
  __shared__ float s_rkinv[RR], s_rkwm[RR];

  const int b = blockIdx.x;
  const int tid = threadIdx.x;
  const int lane = tid & 63;
  const int wid = tid >> 6;
  const int c0 = 2 * tid;             // this thread owns columns c0, c0+1

  // ---------- small-input staging ----------
  float gp = 0.f;
  if (tid < HH) gp = hx[(size_t)b * HH + tid] * Wg[tid];
  if (tid < WW) s_wm[tid] = tanhf(m_t[(size_t)b * WW + tid]);
  if (tid < RR * WW) s_rk[tid] = tanhf(k_r[(size_t)b * (RR * WW) + tid]);

  float ut[2];
  {
    const size_t rb = (size_t)b * RR * NN;
    float2 u2 = *reinterpret_cast<const float2*>(usage + (size_t)b * NN + c0);
    float2 r0 = *reinterpret_cast<const float2*>(read_weights + rb + c0);
    float2 r1 = *reinterpret_cast<const float2*>(read_weights + rb + NN + c0);
    float2 r2 = *reinterpret_cast<const float2*>(read_weights + rb + 2 * NN + c0);
    float2 r3 = *reinterpret_cast<const float2*>(read_weights + rb + 3 * NN + c0);
    ut[0] = 0.7f * u2.x + 0.3f * (r0.x + r1.x + r2.x + r3.x);
    ut[1] = 0.7f * u2.y + 0.3f * (r0.y + r1.y + r2.y + r3.y);
  }

  // gamma = sigmoid(hx @ Wg + bg)   (block_sum barriers publish the LDS above)
  const float gamma = 1.f / (1.f + expf(-(block_sum(gp, s_red) + bg[0])));
  float wmp = (tid < WW) ? s_wm[tid] * s_wm[tid] : 0.f;
  const float wmss = block_sum(wmp, s_red);
  const float inv_wm = 1.f / (sqrtf(wmss) + 1e-8f);

  // per-read-key norms and rk·wm (one wave per r)
  if (wid < RR) {
    const float a = s_rk[wid * WW + lane];
    const float c = s_rk[wid * WW + 64 + lane];
    const float wa = s_wm[lane], wc = s_wm[64 + lane];
    float ss = wave_sum(a * a + c * c);
    float sw = wave_sum(a * wa + c * wc);
    if (lane == 0) {
      s_rkinv[wid] = 1.f / (sqrtf(ss) + 1e-8f);
      s_rkwm[wid] = sw;
    }
  }
  __syncthreads();

  // ---------- phase A: column stats over M ----------
  const size_t base = (size_t)b * WW * NN;
  const float* Mb = memory + base;
  float cn[2] = {0.f, 0.f}, wd[2] = {0.f, 0.f};
  float rd[RR][2];
#pragma unroll
  for (int r = 0; r < RR; ++r) { rd[r][0] = 0.f; rd[r][1] = 0.f; }
#pragma unroll 8
  for (int w = 0; w < WW; ++w) {
    float2 v = *reinterpret_cast<const float2*>(Mb + (size_t)w * NN + c0);
    const float wmw = s_wm[w];
    cn[0] = fmaf(v.x, v.x, cn[0]); wd[0] = fmaf(wmw, v.x, wd[0]);
    cn[1] = fmaf(v.y, v.y, cn[1]); wd[1] = fmaf(wmw, v.y, wd[1]);
#pragma unroll
    for (int r = 0; r < RR; ++r) {
      const float rkw = s_rk[r * WW + w];
      rd[r][0] = fmaf(rkw, v.x, rd[r][0]);
      rd[r][1] = fmaf(rkw, v.y, rd[r][1]);
    }
  }

  // ---------- phase B1: write softmax ----------
  float lg[2], mx = -1e30f;
  {
    float2 nw = *reinterpret_cast<const float2*>(noise_write + (size_t)b * NN + c0);
    const float nwv[2] = {nw.x, nw.y};
#pragma unroll
    for (int j = 0; j < 2; ++j) {
      float dist = wd[j] * inv_wm / (sqrtf(cn[j]) + 1e-8f);
      lg[j] = 1.f + dist - gamma * ut[j] + gumbelf(nwv[j]);
      mx = fmaxf(mx, lg[j]);
    }
  }
  mx = block_max(mx, s_red);
  float ex[2], es = 0.f;
#pragma unroll
  for (int j = 0; j < 2; ++j) { ex[j] = expf(lg[j] - mx); es += ex[j]; }
  es = block_sum(es, s_red);
  const float inv_es = 1.f / es;
  float wtk[2], omw[2];
#pragma unroll
  for (int j = 0; j < 2; ++j) { wtk[j] = ex[j] * inv_es; omw[j] = 1.f - wtk[j]; }
  {
    float2 un;
    un.x = ut[0] * omw[0]; un.y = ut[1] * omw[1];
    *reinterpret_cast<float2*>(usage_new + (size_t)b * NN + c0) = un;
    s_wt[c0] = wtk[0]; s_wt[c0 + 1] = wtk[1];
  }

  // ---------- phase B2: read softmax (analytic stats of mem_new) ----------
  const float invrk[RR] = { s_rkinv[0], s_rkinv[1], s_rkinv[2], s_rkinv[3] };
  const float rkwm[RR]  = { s_rkwm[0], s_rkwm[1], s_rkwm[2], s_rkwm[3] };
  float inv_cn2[2];
#pragma unroll
  for (int j = 0; j < 2; ++j) {
    float cn2 = omw[j] * omw[j] * cn[j]
              + 2.f * omw[j] * wtk[j] * wd[j]
              + wtk[j] * wtk[j] * wmss;
    inv_cn2[j] = 1.f / (sqrtf(cn2) + 1e-8f);
  }
  float lr[RR][2], mr[RR];
#pragma unroll
  for (int r = 0; r < RR; ++r) {
    float2 nr = *reinterpret_cast<const float2*>(
        noise_read + ((size_t)b * RR + r) * NN + c0);
    const float nrv[2] = {nr.x, nr.y};
    float m = -1e30f;
#pragma unroll
    for (int j = 0; j < 2; ++j) {
      float rdn = omw[j] * rd[r][j] + wtk[j] * rkwm[r];
      lr[r][j] = rdn * invrk[r] * inv_cn2[j] + gumbelf(nrv[j]);
      m = fmaxf(m, lr[r][j]);
    }
    mr[r] = m;
  }
  block_max4(mr, s_red);
  float er[RR][2], ers[RR];
#pragma unroll
  for (int r = 0; r < RR; ++r) {
    float s = 0.f;
#pragma unroll
    for (int j = 0; j < 2; ++j) { er[r][j] = expf(lr[r][j] - mr[r]); s += er[r][j]; }
    ers[r] = s;
  }
  block_sum4(ers, s_red);
#pragma unroll
  for (int r = 0; r < RR; ++r) {
    const float inv_ers = 1.f / ers[r];
    float2 o;
    o.x = er[r][0] * inv_ers; o.y = er[r][1] * inv_ers;
    s_rwt[r][c0] = o.x; s_rwt[r][c0 + 1] = o.y;
    *reinterpret_cast<float2*>(read_wt_out + ((size_t)b * RR + r) * NN + c0) = o;
  }
  __syncthreads();

  // ---------- phase C: apply (wave owns 8 rows) ----------
  const int w0 = wid * RPW;
  float wm[RPW];
#pragma unroll
  for (int i = 0; i < RPW; ++i) wm[i] = s_wm[w0 + i];

  float* MNb = mem_new + base;
  float pme[RPW];
  float mrp[RPW][RR];
#pragma unroll
  for (int i = 0; i < RPW; ++i) {
    pme[i] = 0.f;
#pragma unroll
    for (int r = 0; r < RR; ++r) mrp[i][r] = 0.f;
  }

#pragma unroll 1
  for (int ch = 0; ch < NN; ch += 256) {
    const int c = ch + 4 * lane;
    const float4 wt4 = *reinterpret_cast<const float4*>(&s_wt[c]);
    const float ow0 = 1.f - wt4.x, ow1 = 1.f - wt4.y,
                ow2 = 1.f - wt4.z, ow3 = 1.f - wt4.w;
    float4 rw[RR];
#pragma unroll
    for (int r = 0; r < RR; ++r)
      rw[r] = *reinterpret_cast<const float4*>(&s_rwt[r][c]);

#pragma unroll
    for (int i = 0; i < RPW; ++i) {
      const size_t off = (size_t)(w0 + i) * NN + c;
      float4 v = *reinterpret_cast<const float4*>(Mb + off);
      float4 nv;
      nv.x = fmaf(v.x, ow0, wm[i] * wt4.x);
      nv.y = fmaf(v.y, ow1, wm[i] * wt4.y);
      nv.z = fmaf(v.z, ow2, wm[i] * wt4.z);
      nv.w = fmaf(v.w, ow3, wm[i] * wt4.w);
      nfloat4 nvv;
      nvv.x = nv.x; nvv.y = nv.y; nvv.z = nv.z; nvv.w = nv.w;
      __builtin_nontemporal_store(nvv, reinterpret_cast<nfloat4*>(MNb + off));
      float p = wt4.x * v.x;
      p = fmaf(wt4.y, v.y, p);
      p = fmaf(wt4.z, v.z, p);
      p = fmaf(wt4.w, v.w, p);
      pme[i] += p;
#pragma unroll
      for (int r = 0; r < RR; ++r) {
        float a = rw[r].x * nv.x;
        a = fmaf(rw[r].y, nv.y, a);
        a = fmaf(rw[r].z, nv.z, a);
        a = fmaf(rw[r].w, nv.w, a);
        mrp[i][r] += a;
      }
    }
  }

  // 40 independent wave-reduction chains
#pragma unroll
  for (int m = 32; m >= 1; m >>= 1) {
#pragma unroll
    for (int i = 0; i < RPW; ++i) {
      pme[i] += __shfl_xor(pme[i], m, 64);
#pragma unroll
      for (int r = 0; r < RR; ++r) mrp[i][r] += __shfl_xor(mrp[i][r], m, 64);
    }
  }
  if (lane == 0) {
#pragma unroll
    for (int i = 0; i < RPW; ++i) {
      m_erased[(size_t)b * WW + w0 + i] = pme[i];
#pragma unroll
      for (int r = 0; r < RR; ++r)
        m_read[(size_t)b * RR * WW + r * WW + w0 + i] = mrp[i][r];
    }
  }
}

extern "C" void kernel_launch(void* const* d_in, const int* in_sizes, int n_in,
                              void* d_out, int out_size, void* d_ws, size_t ws_size,
                              hipStream_t stream) {
  (void)in_sizes; (void)n_in; (void)d_ws; (void)ws_size; (void)out_size;
  const float* k_r          = (const float*)d_in[0];
  const float* m_t          = (const float*)d_in[1];
  const float* hx           = (const float*)d_in[2];
  const float* memory       = (const float*)d_in[3];
  const float* usage        = (const float*)d_in[4];
  const float* read_weights = (const float*)d_in[5];
  const float* Wg           = (const float*)d_in[6];
  const float* bg           = (const float*)d_in[7];
  const float* noise_write  = (const float*)d_in[8];
  const float* noise_read   = (const float*)d_in[9];

  float* out       = (float*)d_out;
  float* m_read    = out;                                   // BS*RR*WW
  float* mem_new   = m_read + (size_t)BS * RR * WW;         // BS*WW*NN
  float* usage_new = mem_new + (size_t)BS * WW * NN;        // BS*NN
  float* read_wt   = usage_new + (size_t)BS * NN;           // BS*RR*NN
  float* m_erased  = read_wt + (size_t)BS * RR * NN;        // BS*WW

  explicit_mem_fused<<<dim3(BS), dim3(NT), 0, stream>>>(
      k_r, m_t, hx, memory, usage, read_weights, Wg, bg,
      noise_write, noise_read,
      m_read, mem_new, usage_new, read_wt, m_erased);
}

// Round 7
// 162.516 us; speedup vs baseline: 1.3907x; 1.3907x over previous
//
#include <hip/hip_runtime.h>

#define BS   256
#define RR   4
#define WW   128
#define NN   2048
#define HH   256
#define NT   512
#define WH   64            // rows per half-block (K3)
#define NWAVE (NT / 64)    // 8
#define RPW  (WH / NWAVE)  // 8 rows per wave in K3

typedef float nfloat4 __attribute__((ext_vector_type(4)));

__device__ __forceinline__ float wave_sum(float v) {
#pragma unroll
  for (int m = 32; m >= 1; m >>= 1) v += __shfl_xor(v, m, 64);
  return v;
}
__device__ __forceinline__ float wave_max(float v) {
#pragma unroll
  for (int m = 32; m >= 1; m >>= 1) v = fmaxf(v, __shfl_xor(v, m, 64));
  return v;
}
__device__ __forceinline__ float block_sum(float v, float* s_red) {
  const int tid = threadIdx.x;
  v = wave_sum(v);
  __syncthreads();
  if ((tid & 63) == 0) s_red[tid >> 6] = v;
  __syncthreads();
  float s = s_red[0];
#pragma unroll
  for (int i = 1; i < NWAVE; ++i) s += s_red[i];
  return s;
}
__device__ __forceinline__ float block_max(float v, float* s_red) {
  const int tid = threadIdx.x;
  v = wave_max(v);
  __syncthreads();
  if ((tid & 63) == 0) s_red[tid >> 6] = v;
  __syncthreads();
  float s = s_red[0];
#pragma unroll
  for (int i = 1; i < NWAVE; ++i) s = fmaxf(s, s_red[i]);
  return s;
}
__device__ __forceinline__ void block_max4(float v[RR], float* s_red4) {
  const int tid = threadIdx.x, lane = tid & 63, wid = tid >> 6;
#pragma unroll
  for (int m = 32; m >= 1; m >>= 1) {
#pragma unroll
    for (int r = 0; r < RR; ++r) v[r] = fmaxf(v[r], __shfl_xor(v[r], m, 64));
  }
  __syncthreads();
  if (lane == 0) {
#pragma unroll
    for (int r = 0; r < RR; ++r) s_red4[wid * RR + r] = v[r];
  }
  __syncthreads();
#pragma unroll
  for (int r = 0; r < RR; ++r) {
    float s = s_red4[r];
#pragma unroll
    for (int i = 1; i < NWAVE; ++i) s = fmaxf(s, s_red4[i * RR + r]);
    v[r] = s;
  }
}
__device__ __forceinline__ void block_sum4(float v[RR], float* s_red4) {
  const int tid = threadIdx.x, lane = tid & 63, wid = tid >> 6;
#pragma unroll
  for (int m = 32; m >= 1; m >>= 1) {
#pragma unroll
    for (int r = 0; r < RR; ++r) v[r] += __shfl_xor(v[r], m, 64);
  }
  __syncthreads();
  if (lane == 0) {
#pragma unroll
    for (int r = 0; r < RR; ++r) s_red4[wid * RR + r] = v[r];
  }
  __syncthreads();
#pragma unroll
  for (int r = 0; r < RR; ++r) {
    float s = s_red4[r];
#pragma unroll
    for (int i = 1; i < NWAVE; ++i) s += s_red4[i * RR + r];
    v[r] = s;
  }
}
__device__ __forceinline__ float gumbelf(float u) {
  return -logf(-logf(u + 1e-10f) + 1e-10f);
}

// ---------------- K12: stats directly from M + both softmaxes ----------------
// grid 256 (one block per batch), 512 threads, thread owns 4 consecutive cols.
__global__ __launch_bounds__(NT) void k12_stats_softmax(
    const float* __restrict__ k_r, const float* __restrict__ m_t,
    const float* __restrict__ hx, const float* __restrict__ memory,
    const float* __restrict__ usage, const float* __restrict__ read_weights,
    const float* __restrict__ Wg, const float* __restrict__ bg,
    const float* __restrict__ noise_write, const float* __restrict__ noise_read,
    float* __restrict__ wt_out, float* __restrict__ usage_new,
    float* __restrict__ read_wt_out)
{
  __shared__ float s_wm[WW];
  __shared__ float s_rk[RR * WW];
  __shared__ float s_red[NWAVE * RR];
  __shared__ float s_rkinv[RR], s_rkwm[RR];

  const int b = blockIdx.x;
  const int tid = threadIdx.x;
  const int lane = tid & 63;
  const int wid = tid >> 6;
  const int c0 = 4 * tid;

  // ---- small staging ----
  float gp = 0.f;
  if (tid < HH) gp = hx[(size_t)b * HH + tid] * Wg[tid];
  if (tid < WW) s_wm[tid] = tanhf(m_t[(size_t)b * WW + tid]);
  s_rk[tid] = tanhf(k_r[(size_t)b * (RR * WW) + tid]);   // RR*WW == 512

  float ut[4];
  {
    const size_t rb = (size_t)b * RR * NN;
    float4 u4 = *reinterpret_cast<const float4*>(usage + (size_t)b * NN + c0);
    float4 r0 = *reinterpret_cast<const float4*>(read_weights + rb + c0);
    float4 r1 = *reinterpret_cast<const float4*>(read_weights + rb + NN + c0);
    float4 r2 = *reinterpret_cast<const float4*>(read_weights + rb + 2 * NN + c0);
    float4 r3 = *reinterpret_cast<const float4*>(read_weights + rb + 3 * NN + c0);
    ut[0] = 0.7f * u4.x + 0.3f * (r0.x + r1.x + r2.x + r3.x);
    ut[1] = 0.7f * u4.y + 0.3f * (r0.y + r1.y + r2.y + r3.y);
    ut[2] = 0.7f * u4.z + 0.3f * (r0.z + r1.z + r2.z + r3.z);
    ut[3] = 0.7f * u4.w + 0.3f * (r0.w + r1.w + r2.w + r3.w);
  }

  const float gamma = 1.f / (1.f + expf(-(block_sum(gp, s_red) + bg[0])));
  float wmp = (tid < WW) ? s_wm[tid] * s_wm[tid] : 0.f;
  const float wmss = block_sum(wmp, s_red);
  const float inv_wm = 1.f / (sqrtf(wmss) + 1e-8f);

  if (wid < RR) {
    const float a = s_rk[wid * WW + lane];
    const float c = s_rk[wid * WW + 64 + lane];
    const float wa = s_wm[lane], wc = s_wm[64 + lane];
    float ss = wave_sum(a * a + c * c);
    float sw = wave_sum(a * wa + c * wc);
    if (lane == 0) {
      s_rkinv[wid] = 1.f / (sqrtf(ss) + 1e-8f);
      s_rkwm[wid] = sw;
    }
  }
  __syncthreads();

  // ---- column stats over M (float4, deep unroll) ----
  const size_t base = (size_t)b * WW * NN;
  const float* Mb = memory + base;
  float cn[4] = {0.f, 0.f, 0.f, 0.f}, wd[4] = {0.f, 0.f, 0.f, 0.f};
  float rd[RR][4];
#pragma unroll
  for (int r = 0; r < RR; ++r) {
#pragma unroll
    for (int j = 0; j < 4; ++j) rd[r][j] = 0.f;
  }
#pragma unroll 8
  for (int w = 0; w < WW; ++w) {
    float4 v = *reinterpret_cast<const float4*>(Mb + (size_t)w * NN + c0);
    const float wmw = s_wm[w];
    cn[0] = fmaf(v.x, v.x, cn[0]); wd[0] = fmaf(wmw, v.x, wd[0]);
    cn[1] = fmaf(v.y, v.y, cn[1]); wd[1] = fmaf(wmw, v.y, wd[1]);
    cn[2] = fmaf(v.z, v.z, cn[2]); wd[2] = fmaf(wmw, v.z, wd[2]);
    cn[3] = fmaf(v.w, v.w, cn[3]); wd[3] = fmaf(wmw, v.w, wd[3]);
#pragma unroll
    for (int r = 0; r < RR; ++r) {
      const float rkw = s_rk[r * WW + w];
      rd[r][0] = fmaf(rkw, v.x, rd[r][0]);
      rd[r][1] = fmaf(rkw, v.y, rd[r][1]);
      rd[r][2] = fmaf(rkw, v.z, rd[r][2]);
      rd[r][3] = fmaf(rkw, v.w, rd[r][3]);
    }
  }

  // ---- write softmax ----
  float lg[4], mx = -1e30f;
  {
    float4 nw = *reinterpret_cast<const float4*>(noise_write + (size_t)b * NN + c0);
    const float nwv[4] = {nw.x, nw.y, nw.z, nw.w};
#pragma unroll
    for (int j = 0; j < 4; ++j) {
      float dist = wd[j] * inv_wm / (sqrtf(cn[j]) + 1e-8f);
      lg[j] = 1.f + dist - gamma * ut[j] + gumbelf(nwv[j]);
      mx = fmaxf(mx, lg[j]);
    }
  }
  mx = block_max(mx, s_red);
  float ex[4], es = 0.f;
#pragma unroll
  for (int j = 0; j < 4; ++j) { ex[j] = expf(lg[j] - mx); es += ex[j]; }
  es = block_sum(es, s_red);
  const float inv_es = 1.f / es;
  float wtk[4], omw[4];
#pragma unroll
  for (int j = 0; j < 4; ++j) { wtk[j] = ex[j] * inv_es; omw[j] = 1.f - wtk[j]; }
  {
    float4 un, wo;
    un.x = ut[0] * omw[0]; un.y = ut[1] * omw[1];
    un.z = ut[2] * omw[2]; un.w = ut[3] * omw[3];
    *reinterpret_cast<float4*>(usage_new + (size_t)b * NN + c0) = un;
    wo.x = wtk[0]; wo.y = wtk[1]; wo.z = wtk[2]; wo.w = wtk[3];
    *reinterpret_cast<float4*>(wt_out + (size_t)b * NN + c0) = wo;
  }

  // ---- read softmax (analytic mem_new stats) ----
  const float invrk[RR] = { s_rkinv[0], s_rkinv[1], s_rkinv[2], s_rkinv[3] };
  const float rkwm[RR]  = { s_rkwm[0], s_rkwm[1], s_rkwm[2], s_rkwm[3] };
  float inv_cn2[4];
#pragma unroll
  for (int j = 0; j < 4; ++j) {
    float cn2 = omw[j] * omw[j] * cn[j]
              + 2.f * omw[j] * wtk[j] * wd[j]
              + wtk[j] * wtk[j] * wmss;
    inv_cn2[j] = 1.f / (sqrtf(cn2) + 1e-8f);
  }
  float lr[RR][4], mr[RR];
#pragma unroll
  for (int r = 0; r < RR; ++r) {
    float4 nr = *reinterpret_cast<const float4*>(
        noise_read + ((size_t)b * RR + r) * NN + c0);
    const float nrv[4] = {nr.x, nr.y, nr.z, nr.w};
    float m = -1e30f;
#pragma unroll
    for (int j = 0; j < 4; ++j) {
      float rdn = omw[j] * rd[r][j] + wtk[j] * rkwm[r];
      lr[r][j] = rdn * invrk[r] * inv_cn2[j] + gumbelf(nrv[j]);
      m = fmaxf(m, lr[r][j]);
    }
    mr[r] = m;
  }
  block_max4(mr, s_red);
  float er[RR][4], ers[RR];
#pragma unroll
  for (int r = 0; r < RR; ++r) {
    float s = 0.f;
#pragma unroll
    for (int j = 0; j < 4; ++j) { er[r][j] = expf(lr[r][j] - mr[r]); s += er[r][j]; }
    ers[r] = s;
  }
  block_sum4(ers, s_red);
#pragma unroll
  for (int r = 0; r < RR; ++r) {
    const float inv_ers = 1.f / ers[r];
    float4 o;
    o.x = er[r][0] * inv_ers; o.y = er[r][1] * inv_ers;
    o.z = er[r][2] * inv_ers; o.w = er[r][3] * inv_ers;
    *reinterpret_cast<float4*>(read_wt_out + ((size_t)b * RR + r) * NN + c0) = o;
  }
}

// ---------------- K3: mem_new + m_erased + m_read, wave-owns-rows ----------------
__global__ __launch_bounds__(NT, 2) void k3_apply(
    const float* __restrict__ m_t, const float* __restrict__ memory,
    const float* __restrict__ wt_in, const float* __restrict__ read_wt,
    float* __restrict__ mem_new, float* __restrict__ m_read,
    float* __restrict__ m_erased)
{
  __shared__ float s_wt[NN];          // 8 KB  write weights
  __shared__ float s_rwt[RR][NN];     // 32 KB read weights

  const int bid = blockIdx.x;
  const int b = bid >> 1, rh = bid & 1;
  const int tid = threadIdx.x;
  const int lane = tid & 63;
  const int wid = tid >> 6;

  // stage weights into LDS (coalesced float4)
  {
    const int c = 4 * tid;
    float4 w4 = *reinterpret_cast<const float4*>(wt_in + (size_t)b * NN + c);
    *reinterpret_cast<float4*>(&s_wt[c]) = w4;
#pragma unroll
    for (int r = 0; r < RR; ++r) {
      float4 t = *reinterpret_cast<const float4*>(
          read_wt + ((size_t)b * RR + r) * NN + c);
      *reinterpret_cast<float4*>(&s_rwt[r][c]) = t;
    }
  }
  // this wave's 8 row keys
  const int w0 = wid * RPW;           // local row base within the 64-row half
  float wm[RPW];
#pragma unroll
  for (int i = 0; i < RPW; ++i)
    wm[i] = tanhf(m_t[(size_t)b * WW + rh * WH + w0 + i]);
  __syncthreads();

  const size_t hbase = (size_t)b * WW * NN + (size_t)rh * WH * NN;
  const float* Mb = memory + hbase;
  float* MNb = mem_new + hbase;

  float pme[RPW];
  float mrp[RPW][RR];
#pragma unroll
  for (int i = 0; i < RPW; ++i) {
    pme[i] = 0.f;
#pragma unroll
    for (int r = 0; r < RR; ++r) mrp[i][r] = 0.f;
  }

  // column chunks of 256 (64 lanes x float4); weights hoisted per chunk
#pragma unroll 1
  for (int ch = 0; ch < NN; ch += 256) {
    const int c = ch + 4 * lane;
    const float4 wt4 = *reinterpret_cast<const float4*>(&s_wt[c]);
    const float ow0 = 1.f - wt4.x, ow1 = 1.f - wt4.y,
                ow2 = 1.f - wt4.z, ow3 = 1.f - wt4.w;
    float4 rw[RR];
#pragma unroll
    for (int r = 0; r < RR; ++r)
      rw[r] = *reinterpret_cast<const float4*>(&s_rwt[r][c]);

#pragma unroll
    for (int i = 0; i < RPW; ++i) {
      const size_t off = (size_t)(w0 + i) * NN + c;
      float4 v = *reinterpret_cast<const float4*>(Mb + off);
      float4 nv;
      nv.x = fmaf(v.x, ow0, wm[i] * wt4.x);
      nv.y = fmaf(v.y, ow1, wm[i] * wt4.y);
      nv.z = fmaf(v.z, ow2, wm[i] * wt4.z);
      nv.w = fmaf(v.w, ow3, wm[i] * wt4.w);
      nfloat4 nvv;
      nvv.x = nv.x; nvv.y = nv.y; nvv.z = nv.z; nvv.w = nv.w;
      __builtin_nontemporal_store(nvv, reinterpret_cast<nfloat4*>(MNb + off));
      float p = wt4.x * v.x;
      p = fmaf(wt4.y, v.y, p);
      p = fmaf(wt4.z, v.z, p);
      p = fmaf(wt4.w, v.w, p);
      pme[i] += p;
#pragma unroll
      for (int r = 0; r < RR; ++r) {
        float a = rw[r].x * nv.x;
        a = fmaf(rw[r].y, nv.y, a);
        a = fmaf(rw[r].z, nv.z, a);
        a = fmaf(rw[r].w, nv.w, a);
        mrp[i][r] += a;
      }
    }
  }

  // reduce 40 accumulators across the wave (independent chains)
#pragma unroll
  for (int m = 32; m >= 1; m >>= 1) {
#pragma unroll
    for (int i = 0; i < RPW; ++i) {
      pme[i] += __shfl_xor(pme[i], m, 64);
#pragma unroll
      for (int r = 0; r < RR; ++r) mrp[i][r] += __shfl_xor(mrp[i][r], m, 64);
    }
  }
  if (lane == 0) {
    const int wg = rh * WH + w0;      // global row base
#pragma unroll
    for (int i = 0; i < RPW; ++i) {
      m_erased[(size_t)b * WW + wg + i] = pme[i];
#pragma unroll
      for (int r = 0; r < RR; ++r)
        m_read[(size_t)b * RR * WW + r * WW + wg + i] = mrp[i][r];
    }
  }
}

extern "C" void kernel_launch(void* const* d_in, const int* in_sizes, int n_in,
                              void* d_out, int out_size, void* d_ws, size_t ws_size,
                              hipStream_t stream) {
  (void)in_sizes; (void)n_in; (void)ws_size; (void)out_size;
  const float* k_r          = (const float*)d_in[0];
  const float* m_t          = (const float*)d_in[1];
  const float* hx           = (const float*)d_in[2];
  const float* memory       = (const float*)d_in[3];
  const float* usage        = (const float*)d_in[4];
  const float* read_weights = (const float*)d_in[5];
  const float* Wg           = (const float*)d_in[6];
  const float* bg           = (const float*)d_in[7];
  const float* noise_write  = (const float*)d_in[8];
  const float* noise_read   = (const float*)d_in[9];

  float* out       = (float*)d_out;
  float* m_read    = out;                                   // BS*RR*WW
  float* mem_new   = m_read + (size_t)BS * RR * WW;         // BS*WW*NN
  float* usage_new = mem_new + (size_t)BS * WW * NN;        // BS*NN
  float* read_wt   = usage_new + (size_t)BS * NN;           // BS*RR*NN
  float* m_erased  = read_wt + (size_t)BS * RR * NN;        // BS*WW

  float* wt_ws = (float*)d_ws;       // BS*NN floats = 2 MB write weights

  k12_stats_softmax<<<dim3(BS), dim3(NT), 0, stream>>>(
      k_r, m_t, hx, memory, usage, read_weights, Wg, bg,
      noise_write, noise_read, wt_ws, usage_new, read_wt);
  k3_apply<<<dim3(2 * BS), dim3(NT), 0, stream>>>(
      m_t, memory, wt_ws, read_wt, mem_new, m_read, m_erased);
}